// Round 5
// baseline (498.508 us; speedup 1.0000x reference)
//
#include <hip/hip_runtime.h>
#include <hip/hip_bf16.h>

#define NB 262144
#define AA 10
#define DD 10
#define KK 32

// ---- bf16 helpers -----------------------------------------------------------
static __device__ __forceinline__ float b2f(unsigned short h) {
    union { unsigned u; float f; } c; c.u = ((unsigned)h) << 16; return c.f;
}
static __device__ __forceinline__ float bflo(unsigned w) {
    union { unsigned u; float f; } c; c.u = w << 16; return c.f;
}
static __device__ __forceinline__ float bfhi(unsigned w) {
    union { unsigned u; float f; } c; c.u = w & 0xffff0000u; return c.f;
}

// f32-vs-bf16 detection by exponent-field statistics (verified rounds 2-4).
__device__ __forceinline__ int detect_f32(const unsigned short* p, int nshorts,
                                          unsigned expthr, int lane) {
    int bad = 0;
    if (lane < nshorts) {
        unsigned e = (p[lane] >> 7) & 0xFFu;
        bad = (e >= expthr);
    }
    return __any(bad);
}

// One wave per block; one batch per thread.
// Spill-free dataflow (W/X never materialized):
//   phase A, per u: um = U[u]*M; wrow = sum_v relu(um*V[v]) V[v];
//                   us[u] = sum_k pu_k relu(Pu[k]*U[u] + Pi[k]*wrow)
//   phase B, per v: mv = M*V[v]; xrow = sum_u relu(U[u]*mv) U[u];
//                   isc[v] = sum_k pi_k relu(Pi[k]*V[v] + Pu[k]*xrow)
// Peak co-live regs ~240 (U 100 + V 100 + rows) -> fits 256, no scratch.
// LDS cut to 16.5 KB (staging in 32-batch halves) -> ~9 blocks/CU by LDS,
// 8 waves/CU by VGPR (2/SIMD).
__global__ __launch_bounds__(64, 2) void aie_kernel(
    const unsigned short* __restrict__ user_rep,   // [B,10,10]
    const unsigned short* __restrict__ item_rep,   // [B,10,10]
    const unsigned short* __restrict__ wM,         // [10,10]
    const unsigned short* __restrict__ wPu,        // [32,10]
    const unsigned short* __restrict__ wpu,        // [32]
    const unsigned short* __restrict__ wPi,        // [32,10]
    const unsigned short* __restrict__ wpi,        // [32]
    float* __restrict__ out)                       // [2*B*10] f32
{
    __shared__ float sM[100];          // M[d][e] at sM[10d+e]
    __shared__ float sP[KK * 24];      // per k: [0..9]=Pu[k], [12..21]=Pi[k] (16B-aligned)
    __shared__ float spu[KK], spi[KK];
    __shared__ float buf[3200];        // 12.8 KB staging (half input / outputs)

    const int t = threadIdx.x;

    // ---- dtype detection (single wave -> wave-uniform result) ----
    int f = 0;
    f |= detect_f32(user_rep, 64, 137, t) << 0;
    f |= detect_f32(item_rep, 64, 137, t) << 1;
    f |= detect_f32(wM,  64, 125, t) << 2;
    f |= detect_f32(wPu, 64, 125, t) << 3;
    f |= detect_f32(wpu, 32, 125, t) << 4;
    f |= detect_f32(wPi, 64, 125, t) << 5;
    f |= detect_f32(wpi, 32, 125, t) << 6;

    // ---- stage weights to LDS as f32 ----
    {
        const float* fM  = (const float*)wM;
        const float* fPu = (const float*)wPu;
        const float* fPi = (const float*)wPi;
        const float* fpu = (const float*)wpu;
        const float* fpi = (const float*)wpi;
        for (int i = t; i < 100; i += 64) sM[i] = (f & 4) ? fM[i] : b2f(wM[i]);
        for (int i = t; i < KK * DD; i += 64) {
            int k = i / 10, d = i - 10 * k;
            sP[24 * k + d]      = (f & 8)  ? fPu[i] : b2f(wPu[i]);
            sP[24 * k + 12 + d] = (f & 32) ? fPi[i] : b2f(wPi[i]);
        }
        if (t < KK) {
            spu[t] = (f & 16) ? fpu[t] : b2f(wpu[t]);
            spi[t] = (f & 64) ? fpi[t] : b2f(wpi[t]);
        }
    }
    __syncthreads();

    const int blk = blockIdx.x;
    float U[AA][DD], V[AA][DD];

    // ---- stage & unpack item_rep -> V, in two 32-batch halves ----
    #pragma unroll 1
    for (int h = 0; h < 2; h++) {
        if (f & 2) {
            const float4* g = (const float4*)((const float*)item_rep
                              + (size_t)blk * 6400 + h * 3200);
            #pragma unroll
            for (int j = 0; j < 13; j++) {
                int m = t + 64 * j;
                if (m < 800) ((float4*)buf)[m] = g[m];
            }
        } else {
            const uint2* g = (const uint2*)(item_rep + (size_t)blk * 6400 + h * 3200);
            #pragma unroll
            for (int j = 0; j < 13; j++) {
                int m = t + 64 * j;
                if (m < 800) {
                    uint2 w = g[m];
                    ((float4*)buf)[m] = make_float4(bflo(w.x), bfhi(w.x),
                                                    bflo(w.y), bfhi(w.y));
                }
            }
        }
        __syncthreads();
        if ((t >> 5) == h) {
            const float2* mine = (const float2*)(buf + 100 * (t & 31));
            #pragma unroll
            for (int j = 0; j < 50; j++) {
                float2 w = mine[j]; int e = 2 * j;
                V[e / 10][e % 10]             = w.x;
                V[(e + 1) / 10][(e + 1) % 10] = w.y;
            }
        }
        __syncthreads();
    }

    // ---- stage & unpack user_rep -> U ----
    #pragma unroll 1
    for (int h = 0; h < 2; h++) {
        if (f & 1) {
            const float4* g = (const float4*)((const float*)user_rep
                              + (size_t)blk * 6400 + h * 3200);
            #pragma unroll
            for (int j = 0; j < 13; j++) {
                int m = t + 64 * j;
                if (m < 800) ((float4*)buf)[m] = g[m];
            }
        } else {
            const uint2* g = (const uint2*)(user_rep + (size_t)blk * 6400 + h * 3200);
            #pragma unroll
            for (int j = 0; j < 13; j++) {
                int m = t + 64 * j;
                if (m < 800) {
                    uint2 w = g[m];
                    ((float4*)buf)[m] = make_float4(bflo(w.x), bfhi(w.x),
                                                    bflo(w.y), bfhi(w.y));
                }
            }
        }
        __syncthreads();
        if ((t >> 5) == h) {
            const float2* mine = (const float2*)(buf + 100 * (t & 31));
            #pragma unroll
            for (int j = 0; j < 50; j++) {
                float2 w = mine[j]; int e = 2 * j;
                U[e / 10][e % 10]             = w.x;
                U[(e + 1) / 10][(e + 1) % 10] = w.y;
            }
        }
        __syncthreads();
    }

    // ---- phase A: user branch, row-streaming (no W array) ----
    float us[AA];
    #pragma unroll
    for (int u = 0; u < AA; u++) {
        float um[DD];
        #pragma unroll
        for (int e = 0; e < DD; e++) {
            float a = U[u][0] * sM[e];
            #pragma unroll
            for (int d = 1; d < DD; d++) a += U[u][d] * sM[10 * d + e];
            um[e] = a;
        }
        float wrow[DD];
        #pragma unroll
        for (int d = 0; d < DD; d++) wrow[d] = 0.f;
        #pragma unroll
        for (int v = 0; v < AA; v++) {
            float r = um[0] * V[v][0];
            #pragma unroll
            for (int e = 1; e < DD; e++) r += um[e] * V[v][e];
            r = fmaxf(r, 0.f);
            #pragma unroll
            for (int d = 0; d < DD; d++) wrow[d] += r * V[v][d];
        }
        float su = 0.f;
        #pragma unroll 2
        for (int k = 0; k < KK; k++) {
            const float* pk = sP + 24 * k;
            float a = pk[0] * U[u][0], b = pk[12] * wrow[0];
            #pragma unroll
            for (int d = 1; d < DD; d++) {
                a += pk[d] * U[u][d];
                b += pk[12 + d] * wrow[d];
            }
            su += spu[k] * fmaxf(a + b, 0.f);
        }
        us[u] = su;
    }

    // ---- softmax(us) -> buf[11t+u] ----
    {
        float mx = us[0];
        #pragma unroll
        for (int u = 1; u < AA; u++) mx = fmaxf(mx, us[u]);
        float s = 0.f;
        #pragma unroll
        for (int u = 0; u < AA; u++) { us[u] = __expf(us[u] - mx); s += us[u]; }
        float inv = 1.f / s;
        #pragma unroll
        for (int u = 0; u < AA; u++) buf[11 * t + u] = us[u] * inv;
    }

    // ---- phase B: item branch, column-streaming (no X array) ----
    float isc[AA];
    #pragma unroll
    for (int v = 0; v < AA; v++) {
        float mv[DD];
        #pragma unroll
        for (int d = 0; d < DD; d++) {
            float a = sM[10 * d] * V[v][0];
            #pragma unroll
            for (int e = 1; e < DD; e++) a += sM[10 * d + e] * V[v][e];
            mv[d] = a;
        }
        float xrow[DD];
        #pragma unroll
        for (int d = 0; d < DD; d++) xrow[d] = 0.f;
        #pragma unroll
        for (int u = 0; u < AA; u++) {
            float r = U[u][0] * mv[0];
            #pragma unroll
            for (int d = 1; d < DD; d++) r += U[u][d] * mv[d];
            r = fmaxf(r, 0.f);
            #pragma unroll
            for (int d = 0; d < DD; d++) xrow[d] += r * U[u][d];
        }
        float sv = 0.f;
        #pragma unroll 2
        for (int k = 0; k < KK; k++) {
            const float* pk = sP + 24 * k;
            float a = pk[12] * V[v][0], b = pk[0] * xrow[0];
            #pragma unroll
            for (int d = 1; d < DD; d++) {
                a += pk[12 + d] * V[v][d];
                b += pk[d] * xrow[d];
            }
            sv += spi[k] * fmaxf(a + b, 0.f);
        }
        isc[v] = sv;
    }

    // ---- softmax(isc) -> buf[704 + 11t+v] ----
    {
        float mx = isc[0];
        #pragma unroll
        for (int v = 1; v < AA; v++) mx = fmaxf(mx, isc[v]);
        float s = 0.f;
        #pragma unroll
        for (int v = 0; v < AA; v++) { isc[v] = __expf(isc[v] - mx); s += isc[v]; }
        float inv = 1.f / s;
        #pragma unroll
        for (int v = 0; v < AA; v++) buf[704 + 11 * t + v] = isc[v] * inv;
    }
    __syncthreads();

    // ---- coalesced output stores (float2 streams) ----
    {
        float2* o0 = (float2*)(out + (size_t)blk * 640);
        float2* o1 = (float2*)(out + (size_t)NB * 10 + (size_t)blk * 640);
        #pragma unroll
        for (int j = 0; j < 5; j++) {
            int m = t + 64 * j;
            int i = m / 5;
            int u = 2 * (m - 5 * i);
            o0[m] = make_float2(buf[11 * i + u],       buf[11 * i + u + 1]);
            o1[m] = make_float2(buf[704 + 11 * i + u], buf[704 + 11 * i + u + 1]);
        }
    }
}

extern "C" void kernel_launch(void* const* d_in, const int* in_sizes, int n_in,
                              void* d_out, int out_size, void* d_ws, size_t ws_size,
                              hipStream_t stream) {
    const unsigned short* user_rep = (const unsigned short*)d_in[0];
    const unsigned short* item_rep = (const unsigned short*)d_in[1];
    const unsigned short* wM       = (const unsigned short*)d_in[2];
    const unsigned short* wPu      = (const unsigned short*)d_in[3];
    const unsigned short* wpu      = (const unsigned short*)d_in[4];
    const unsigned short* wPi      = (const unsigned short*)d_in[5];
    const unsigned short* wpi      = (const unsigned short*)d_in[6];
    float* out                     = (float*)d_out;

    dim3 block(64);
    dim3 grid(NB / 64);   // 4096 blocks
    hipLaunchKernelGGL(aie_kernel, grid, block, 0, stream,
                       user_rep, item_rep, wM, wPu, wpu, wPi, wpi, out);
}